// Round 6
// baseline (2832.529 us; speedup 1.0000x reference)
//
#include <hip/hip_runtime.h>

typedef unsigned short u16;
typedef unsigned int u32;
typedef unsigned long long u64;
typedef __attribute__((ext_vector_type(8))) short short8;
typedef __attribute__((ext_vector_type(4))) float f32x4;

__device__ __forceinline__ float bf2f(u16 u) {
  union { float f; unsigned int i; } x; x.i = ((unsigned int)u) << 16; return x.f;
}
__device__ __forceinline__ u16 f2bf(float f) {
  union { float f; unsigned int i; } x; x.f = f;
  unsigned int r = x.i + 0x7FFFu + ((x.i >> 16) & 1u);
  return (u16)(r >> 16);
}
__device__ __forceinline__ float sigmf(float x) { return 1.f / (1.f + __expf(-x)); }
__device__ __forceinline__ float tanhfast(float x) { return 1.f - 2.f / (__expf(2.f * x) + 1.f); }

// ---------------------------------------------------------------------------
// elementwise fp32 -> bf16 convert
__global__ __launch_bounds__(256) void f2bf_kernel(const float* __restrict__ src,
                                                   u16* __restrict__ dst, int n) {
  int i = blockIdx.x * 256 + threadIdx.x;
  if (i < n) dst[i] = f2bf(src[i]);
}

// pack Wq|Wk|Wv -> [512][192] bf16, bq|bk|bv -> [192] fp32
__global__ __launch_bounds__(256) void pack_qkv_kernel(
    const float* __restrict__ Wq, const float* __restrict__ Wk, const float* __restrict__ Wv,
    const float* __restrict__ bq, const float* __restrict__ bk, const float* __restrict__ bv,
    u16* __restrict__ Wp, float* __restrict__ bp) {
  int i = blockIdx.x * 256 + threadIdx.x;
  if (i < 512 * 192) {
    int k = i / 192, r = i % 192, s = r >> 6, c = r & 63;
    const float* W = (s == 0) ? Wq : ((s == 1) ? Wk : Wv);
    Wp[i] = f2bf(W[k * 64 + c]);
  }
  if (i < 192) {
    int s = i >> 6, c = i & 63;
    bp[i] = ((s == 0) ? bq : ((s == 1) ? bk : bv))[c];
  }
}

// ---------------------------------------------------------------------------
// generic bf16 MFMA GEMM: C[M,N] = A[M,K] @ B[K,N] + bias.
// mode 0: plain (Cf fp32 and/or Cb bf16). mode 1: sigmoid -> Cf.
// mode 2: qkvT store -> Cf[sel][b][head][d][t] float4 along t (M=b*512+t, N=192).
__global__ __launch_bounds__(256) void gemm_bf16(
    const u16* __restrict__ A, const u16* __restrict__ B, const float* __restrict__ bias,
    float* __restrict__ Cf, u16* __restrict__ Cb, int M, int N, int K, int mode) {
  __shared__ u16 As[64][72];
  __shared__ u16 Bs[64][72];  // transposed: Bs[n][k]
  int tid = threadIdx.x;
  int tm = blockIdx.x * 64, tn = blockIdx.y * 64;
  int w = tid >> 6, L = tid & 63, m15 = L & 15, q = L >> 4;
  int lr = tid >> 3, lk = (tid & 7) * 8;

  f32x4 zero = {0.f, 0.f, 0.f, 0.f};
  f32x4 acc[4];
#pragma unroll
  for (int j = 0; j < 4; ++j) acc[j] = zero;

  for (int tk = 0; tk < K; tk += 64) {
#pragma unroll
    for (int rr = lr; rr < 64; rr += 32) {
      short8 v = *(const short8*)(A + (size_t)(tm + rr) * K + tk + lk);
      *(short8*)&As[rr][lk] = v;
    }
#pragma unroll
    for (int rr = lr; rr < 64; rr += 32) {
      short8 v = *(const short8*)(B + (size_t)(tk + rr) * N + tn + lk);
      const short* pv = (const short*)&v;
#pragma unroll
      for (int j = 0; j < 8; ++j) Bs[lk + j][rr] = (u16)pv[j];
    }
    __syncthreads();
#pragma unroll
    for (int ks = 0; ks < 2; ++ks) {
      int k0 = ks * 32 + q * 8;
      short8 a = *(const short8*)&As[w * 16 + m15][k0];
#pragma unroll
      for (int j = 0; j < 4; ++j) {
        short8 b = *(const short8*)&Bs[j * 16 + m15][k0];
        acc[j] = __builtin_amdgcn_mfma_f32_16x16x32_bf16(a, b, acc[j], 0, 0, 0);
      }
    }
    __syncthreads();
  }
  if (mode == 2) {
    int row0 = tm + w * 16 + q * 4;
    int bq_ = row0 >> 9, t0 = row0 & 511;
#pragma unroll
    for (int j = 0; j < 4; ++j) {
      int col = tn + j * 16 + m15;
      int sel = col >> 6, cc = col & 63, hd = cc >> 3, d = cc & 7;
      float bia = bias ? bias[col] : 0.f;
      f32x4 vv;
#pragma unroll
      for (int r = 0; r < 4; ++r) vv[r] = acc[j][r] + bia;
      *(f32x4*)(Cf + ((((size_t)sel * 16 + bq_) * 8 + hd) * 8 + d) * 512 + t0) = vv;
    }
    return;
  }
#pragma unroll
  for (int j = 0; j < 4; ++j) {
    int col = tn + j * 16 + m15;
    float bia = bias ? bias[col] : 0.f;
#pragma unroll
    for (int r = 0; r < 4; ++r) {
      int row = tm + w * 16 + q * 4 + r;
      float v = acc[j][r] + bia;
      if (mode == 1) v = sigmf(v);
      if (Cf) Cf[(size_t)row * N + col] = v;
      if (Cb) Cb[(size_t)row * N + col] = f2bf(v);
    }
  }
}

// ---------------------------------------------------------------------------
// Persistent LSTM scan: 8 wgs x 512 threads (8 waves); wave w of wg g owns
// hidden units 64g+8w..+7 (its 32 Wh gate-columns live in VGPRs).
// Exchange protocol (tagged, flag-free): each h bf16-pair is stored as
//   u64 {tag=t+1, pair} with ONE relaxed agent store (no drain, no flag).
// Immediately after storing, every thread issues its 8 all-gather u64 loads,
// overlaps hs-stores + xg-prefetch with their flight, then tag-checks and
// selectively retries stale entries (symmetric timing -> ~1-2 rounds).
// ONE __syncthreads per step. h_buf parity-double-buffered; tag==t+1 exactly
// (previous parity tag t-1 can't false-positive; 0xAA poison can't either).
__global__ __launch_bounds__(512, 2) void lstm_kernel(
    const float* __restrict__ Wh,   // [512][2048] fp32
    const u16* __restrict__ xg,     // [8192][2048] bf16 (x@Wx + b)
    float* __restrict__ hs,         // [8192][512] fp32 out
    u64* __restrict__ h_buf)        // [2][4096] {tag, 2xbf16}
{
  __shared__ u16 hL[2][16][520];

  int tid = threadIdx.x;
  int wv = tid >> 6, L = tid & 63, m15 = L & 15, q = L >> 4;
  int u0w = blockIdx.x * 64 + wv * 8;  // first hidden unit of this wave

  // zero hL[0] (h_{-1} = 0)
  for (int i = tid; i < 16 * 520; i += 512) ((u16*)hL[0])[i] = 0;

  // preload Wh B-fragments into registers (step-invariant).
  // bfrag[kt][tl]: B[k=kt*32+q*8+jj][n=tl*16+m15], col=(n>>3)*512+u0w+(n&7)
  short8 bfrag[16][2];
  float cst[4] = {0.f, 0.f, 0.f, 0.f};
#pragma unroll
  for (int kt = 0; kt < 16; ++kt) {
#pragma unroll
    for (int tl = 0; tl < 2; ++tl) {
      int n = tl * 16 + m15;
      int col = (n >> 3) * 512 + u0w + (n & 7);
      short8 tmp;
#pragma unroll
      for (int jj = 0; jj < 8; ++jj)
        tmp[jj] = (short)f2bf(Wh[(size_t)(kt * 32 + q * 8 + jj) * 2048 + col]);
      bfrag[kt][tl] = tmp;
    }
  }

  // xg prefetch for t=0
  float xv[4][4];
  if (m15 < 8) {
#pragma unroll
    for (int r = 0; r < 4; ++r) {
      size_t base = ((size_t)((q * 4 + r) * 512)) * 2048 + u0w + m15;
#pragma unroll
      for (int g = 0; g < 4; ++g) xv[g][r] = bf2f(xg[base + g * 512]);
    }
  }
  __syncthreads();

  int p = 0;
#pragma unroll 1
  for (int t = 0; t < 512; ++t) {
    u64* hb = h_buf + (size_t)(t & 1) * 4096;

    // 4 independent MFMA chains of depth 8 (A rows = batch, from LDS)
    f32x4 z = {0.f, 0.f, 0.f, 0.f};
    f32x4 a0e = z, a0o = z, a1e = z, a1o = z;
#pragma unroll
    for (int kt = 0; kt < 8; ++kt) {
      short8 aE = *(const short8*)&hL[p][m15][(2 * kt) * 32 + q * 8];
      short8 aO = *(const short8*)&hL[p][m15][(2 * kt + 1) * 32 + q * 8];
      a0e = __builtin_amdgcn_mfma_f32_16x16x32_bf16(aE, bfrag[2 * kt][0], a0e, 0, 0, 0);
      a1e = __builtin_amdgcn_mfma_f32_16x16x32_bf16(aE, bfrag[2 * kt][1], a1e, 0, 0, 0);
      a0o = __builtin_amdgcn_mfma_f32_16x16x32_bf16(aO, bfrag[2 * kt + 1][0], a0o, 0, 0, 0);
      a1o = __builtin_amdgcn_mfma_f32_16x16x32_bf16(aO, bfrag[2 * kt + 1][1], a1o, 0, 0, 0);
    }
    f32x4 acc0, acc1;
#pragma unroll
    for (int r = 0; r < 4; ++r) { acc0[r] = a0e[r] + a0o[r]; acc1[r] = a1e[r] + a1o[r]; }
    // acc0 = i(m15<8)|f ; acc1 = g|o. Gather f,o into low lanes via lane^8.
    f32x4 accf, acco;
#pragma unroll
    for (int r = 0; r < 4; ++r) {
      accf[r] = __shfl_xor(acc0[r], 8);
      acco[r] = __shfl_xor(acc1[r], 8);
    }
    float hv[4] = {0.f, 0.f, 0.f, 0.f};
    unsigned int mybf[4] = {0, 0, 0, 0};
    if (m15 < 8) {
#pragma unroll
      for (int r = 0; r < 4; ++r) {
        float gi = acc0[r] + xv[0][r];
        float gf = accf[r] + xv[1][r];
        float gg = acc1[r] + xv[2][r];
        float go = acco[r] + xv[3][r];
        cst[r] = sigmf(gf) * cst[r] + sigmf(gi) * tanhfast(gg);
        hv[r] = sigmf(go) * tanhfast(cst[r]);
        mybf[r] = (unsigned int)f2bf(hv[r]);
      }
    }

    if (t == 511) {  // last step: no exchange needed
      if (m15 < 8) {
#pragma unroll
        for (int r = 0; r < 4; ++r)
          hs[((size_t)((q * 4 + r) * 512) + t) * 512 + u0w + m15] = hv[r];
      }
      break;
    }

    // tagged h stores: ONE relaxed agent u64 per pair — fire and forget
    unsigned int target = (unsigned int)(t + 1);
#pragma unroll
    for (int r = 0; r < 4; ++r) {
      unsigned int ob = (unsigned int)__shfl_xor((int)mybf[r], 1);
      if (m15 < 8 && (m15 & 1) == 0) {
        u64 val = ((u64)target << 32) | (u64)(mybf[r] | (ob << 16));
        __hip_atomic_store(&hb[(q * 4 + r) * 256 + ((u0w + m15) >> 1)], val,
                           __ATOMIC_RELAXED, __HIP_MEMORY_SCOPE_AGENT);
      }
    }

    // all-gather issue: 8 u64 per thread (32KB total), coalesced
    u64 v[8];
#pragma unroll
    for (int j = 0; j < 8; ++j)
      v[j] = __hip_atomic_load(&hb[j * 512 + tid],
                               __ATOMIC_RELAXED, __HIP_MEMORY_SCOPE_AGENT);

    // overlap with gather flight: xg prefetch t+1, deferred hs stores
    if (m15 < 8) {
#pragma unroll
      for (int r = 0; r < 4; ++r) {
        size_t base = ((size_t)((q * 4 + r) * 512 + t + 1)) * 2048 + u0w + m15;
#pragma unroll
        for (int g = 0; g < 4; ++g) xv[g][r] = bf2f(xg[base + g * 512]);
      }
#pragma unroll
      for (int r = 0; r < 4; ++r)
        hs[((size_t)((q * 4 + r) * 512) + t) * 512 + u0w + m15] = hv[r];
    }

    // tag-check + selective retry (symmetric issue timing -> few rounds)
    for (;;) {
      unsigned int need = 0;
#pragma unroll
      for (int j = 0; j < 8; ++j)
        need |= ((unsigned int)((unsigned int)(v[j] >> 32) != target)) << j;
      if (need == 0) break;
#pragma unroll
      for (int j = 0; j < 8; ++j)
        if (need & (1u << j))
          v[j] = __hip_atomic_load(&hb[j * 512 + tid],
                                   __ATOMIC_RELAXED, __HIP_MEMORY_SCOPE_AGENT);
    }

    // LDS fill: e = j*512+tid -> row e>>8, pair e&255 (u32 = 2 bf16)
#pragma unroll
    for (int j = 0; j < 8; ++j) {
      int e = j * 512 + tid;
      *(u32*)&hL[p ^ 1][e >> 8][(e & 255) * 2] = (u32)v[j];
    }
    __syncthreads();
    p ^= 1;
  }
}

// ---------------------------------------------------------------------------
// LN1: y = LN(hs)*scale + bias + x ; writes fp32 + bf16. One wave per row.
__global__ __launch_bounds__(256) void ln1_kernel(
    const float* __restrict__ hsin, const float* __restrict__ x,
    const float* __restrict__ sc, const float* __restrict__ bi,
    float* __restrict__ hF, u16* __restrict__ hB) {
  int wv = threadIdx.x >> 6, ln = threadIdx.x & 63;
  size_t row = (size_t)blockIdx.x * 4 + wv;
  size_t rb = row * 512;
  float v[8];
  float s = 0.f;
#pragma unroll
  for (int j = 0; j < 8; ++j) { v[j] = hsin[rb + ln + j * 64]; s += v[j]; }
#pragma unroll
  for (int off = 32; off; off >>= 1) s += __shfl_xor(s, off);
  float mu = s * (1.f / 512.f);
  float vs = 0.f;
#pragma unroll
  for (int j = 0; j < 8; ++j) { float d = v[j] - mu; vs += d * d; }
#pragma unroll
  for (int off = 32; off; off >>= 1) vs += __shfl_xor(vs, off);
  float rs = rsqrtf(vs * (1.f / 512.f) + 1e-6f);
#pragma unroll
  for (int j = 0; j < 8; ++j) {
    int cc = ln + j * 64;
    float y = (v[j] - mu) * rs * sc[cc] + bi[cc] + x[rb + cc];
    hF[rb + cc] = y;
    hB[rb + cc] = f2bf(y);
  }
}

// LN2: out = LN(ao*gate + skip)*scale + bias
__global__ __launch_bounds__(256) void ln2_kernel(
    const float* __restrict__ ao, const float* __restrict__ gate,
    const float* __restrict__ skip, const float* __restrict__ sc,
    const float* __restrict__ bi, float* __restrict__ out) {
  int wv = threadIdx.x >> 6, ln = threadIdx.x & 63;
  size_t row = (size_t)blockIdx.x * 4 + wv;
  size_t rb = row * 512;
  float v[8];
  float s = 0.f;
#pragma unroll
  for (int j = 0; j < 8; ++j) {
    size_t ix = rb + ln + j * 64;
    v[j] = ao[ix] * gate[ix] + skip[ix];
    s += v[j];
  }
#pragma unroll
  for (int off = 32; off; off >>= 1) s += __shfl_xor(s, off);
  float mu = s * (1.f / 512.f);
  float vs = 0.f;
#pragma unroll
  for (int j = 0; j < 8; ++j) { float d = v[j] - mu; vs += d * d; }
#pragma unroll
  for (int off = 32; off; off >>= 1) vs += __shfl_xor(vs, off);
  float rs = rsqrtf(vs * (1.f / 512.f) + 1e-6f);
#pragma unroll
  for (int j = 0; j < 8; ++j) {
    int cc = ln + j * 64;
    out[rb + cc] = (v[j] - mu) * rs * sc[cc] + bi[cc];
  }
}

// ---------------------------------------------------------------------------
// attention on transposed qkvT[sel][b][head][d][t]: fully coalesced staging.
// one wg per (b, head); 512 threads = 1 query each; K/V in LDS [t][d] padded.
__global__ __launch_bounds__(512) void attn_kernel(const float* __restrict__ qkvT,
                                                   u16* __restrict__ ctx) {
  __shared__ float kL[512][9];
  __shared__ float vL[512][9];
  int tid = threadIdx.x;
  int b = blockIdx.x >> 3, hd = blockIdx.x & 7;
  const float* qb = qkvT + (((size_t)0 * 16 + b) * 8 + hd) * 8 * 512;
  const float* kb = qkvT + (((size_t)1 * 16 + b) * 8 + hd) * 8 * 512;
  const float* vb = qkvT + (((size_t)2 * 16 + b) * 8 + hd) * 8 * 512;
#pragma unroll
  for (int i = tid; i < 4096; i += 512) {
    int d = i >> 9, t = i & 511;
    kL[t][d] = kb[(size_t)d * 512 + t];
    vL[t][d] = vb[(size_t)d * 512 + t];
  }
  const float scl = 0.35355339059327373f;  // 1/sqrt(8)
  float qv[8];
#pragma unroll
  for (int d = 0; d < 8; ++d) qv[d] = qb[(size_t)d * 512 + tid] * scl;
  __syncthreads();
  float m = -1e30f, l = 0.f;
  float a[8] = {0, 0, 0, 0, 0, 0, 0, 0};
  for (int t2 = 0; t2 < 512; ++t2) {
    float s = 0.f;
#pragma unroll
    for (int d = 0; d < 8; ++d) s += qv[d] * kL[t2][d];
    float nm = fmaxf(m, s);
    float cor = __expf(m - nm);
    float e = __expf(s - nm);
    l = l * cor + e;
#pragma unroll
    for (int d = 0; d < 8; ++d) a[d] = a[d] * cor + e * vL[t2][d];
    m = nm;
  }
  float inv = 1.f / l;
  short8 o;
#pragma unroll
  for (int d = 0; d < 8; ++d) o[d] = (short)f2bf(a[d] * inv);
  *(short8*)(ctx + ((size_t)b * 512 + tid) * 64 + hd * 8) = o;
}

// ---------------------------------------------------------------------------
extern "C" void kernel_launch(void* const* d_in, const int* in_sizes, int n_in,
                              void* d_out, int out_size, void* d_ws, size_t ws_size,
                              hipStream_t stream) {
  (void)in_sizes; (void)n_in; (void)out_size; (void)ws_size;
  const float* x    = (const float*)d_in[0];
  const float* Wx   = (const float*)d_in[1];
  const float* Wh   = (const float*)d_in[2];
  const float* bls  = (const float*)d_in[3];
  const float* ln1s = (const float*)d_in[4];
  const float* ln1b = (const float*)d_in[5];
  const float* Wq   = (const float*)d_in[6];
  const float* bq   = (const float*)d_in[7];
  const float* Wk   = (const float*)d_in[8];
  const float* bk   = (const float*)d_in[9];
  const float* Wv   = (const float*)d_in[10];
  const float* bv   = (const float*)d_in[11];
  const float* Wo   = (const float*)d_in[12];
  const float* bo   = (const float*)d_in[13];
  const float* Wg   = (const float*)d_in[14];
  const float* bg   = (const float*)d_in[15];
  const float* ln2s = (const float*)d_in[16];
  const float* ln2b = (const float*)d_in[17];
  float* out = (float*)d_out;

  char* p = (char*)d_ws;
  auto alloc = [&](size_t bytes) -> char* {
    char* r = p;
    p += (bytes + 255) & ~(size_t)255;
    return r;
  };
  u64* h_buf    = (u64*)alloc((size_t)2 * 4096 * 8);
  u16* x_bf     = (u16*)alloc((size_t)8192 * 512 * 2);
  u16* Wx_bf    = (u16*)alloc((size_t)512 * 2048 * 2);
  u16* Wqkv_bf  = (u16*)alloc((size_t)512 * 192 * 2);
  float* bqkv   = (float*)alloc(192 * 4);
  u16* Wg_bf    = (u16*)alloc((size_t)512 * 512 * 2);
  u16* Wo_bf    = (u16*)alloc((size_t)64 * 512 * 2);
  u16* xg_bf    = (u16*)alloc((size_t)8192 * 2048 * 2);
  float* hs     = (float*)alloc((size_t)8192 * 512 * 4);
  float* hF     = (float*)alloc((size_t)8192 * 512 * 4);
  u16* hB       = (u16*)alloc((size_t)8192 * 512 * 2);
  float* qkvT   = (float*)alloc((size_t)3 * 16 * 8 * 8 * 512 * 4);
  float* gatep  = (float*)alloc((size_t)8192 * 512 * 4);
  u16* ctx      = (u16*)alloc((size_t)8192 * 64 * 2);
  float* ao     = (float*)alloc((size_t)8192 * 512 * 4);

  f2bf_kernel<<<16384, 256, 0, stream>>>(x, x_bf, 8192 * 512);
  f2bf_kernel<<<4096, 256, 0, stream>>>(Wx, Wx_bf, 512 * 2048);
  f2bf_kernel<<<1024, 256, 0, stream>>>(Wg, Wg_bf, 512 * 512);
  f2bf_kernel<<<128, 256, 0, stream>>>(Wo, Wo_bf, 64 * 512);
  pack_qkv_kernel<<<384, 256, 0, stream>>>(Wq, Wk, Wv, bq, bk, bv, Wqkv_bf, bqkv);

  // xg = x @ Wx + b  -> bf16 [8192,2048]
  gemm_bf16<<<dim3(128, 32), 256, 0, stream>>>(x_bf, Wx_bf, bls, nullptr, xg_bf,
                                               8192, 2048, 512, 0);
  // LSTM scan -> hs fp32 [8192,512]
  lstm_kernel<<<8, 512, 0, stream>>>(Wh, xg_bf, hs, h_buf);
  // h = LN(hs)+x  -> hF fp32, hB bf16
  ln1_kernel<<<2048, 256, 0, stream>>>(hs, x, ln1s, ln1b, hF, hB);
  // qkv = h @ [Wq|Wk|Wv] + b  -> qkvT[sel][b][head][d][t] fp32
  gemm_bf16<<<dim3(128, 3), 256, 0, stream>>>(hB, Wqkv_bf, bqkv, qkvT, nullptr,
                                              8192, 192, 512, 2);
  // gate = sigmoid(h @ Wg + bg)  -> fp32 [8192,512]
  gemm_bf16<<<dim3(128, 8), 256, 0, stream>>>(hB, Wg_bf, bg, gatep, nullptr,
                                              8192, 512, 512, 1);
  // attention -> ctx bf16 [8192,64]
  attn_kernel<<<128, 512, 0, stream>>>(qkvT, ctx);
  // attn_out = ctx @ Wo + bo -> fp32 [8192,512]
  gemm_bf16<<<dim3(128, 8), 256, 0, stream>>>(ctx, Wo_bf, bo, ao, nullptr,
                                              8192, 512, 64, 0);
  // out = LN(ao*gate + h)
  ln2_kernel<<<2048, 256, 0, stream>>>(ao, gatep, hF, ln2s, ln2b, out);
}

// Round 7
// 2661.546 us; speedup vs baseline: 1.0642x; 1.0642x over previous
//
#include <hip/hip_runtime.h>

typedef unsigned short u16;
typedef unsigned int u32;
typedef unsigned long long u64;
typedef __attribute__((ext_vector_type(8))) short short8;
typedef __attribute__((ext_vector_type(4))) float f32x4;

__device__ __forceinline__ float bf2f(u16 u) {
  union { float f; unsigned int i; } x; x.i = ((unsigned int)u) << 16; return x.f;
}
__device__ __forceinline__ u16 f2bf(float f) {
  union { float f; unsigned int i; } x; x.f = f;
  unsigned int r = x.i + 0x7FFFu + ((x.i >> 16) & 1u);
  return (u16)(r >> 16);
}
__device__ __forceinline__ float sigmf(float x) { return 1.f / (1.f + __expf(-x)); }
__device__ __forceinline__ float tanhfast(float x) { return 1.f - 2.f / (__expf(2.f * x) + 1.f); }

// ---------------------------------------------------------------------------
// elementwise fp32 -> bf16 convert
__global__ __launch_bounds__(256) void f2bf_kernel(const float* __restrict__ src,
                                                   u16* __restrict__ dst, int n) {
  int i = blockIdx.x * 256 + threadIdx.x;
  if (i < n) dst[i] = f2bf(src[i]);
}

// pack Wq|Wk|Wv -> [512][192] bf16, bq|bk|bv -> [192] fp32
__global__ __launch_bounds__(256) void pack_qkv_kernel(
    const float* __restrict__ Wq, const float* __restrict__ Wk, const float* __restrict__ Wv,
    const float* __restrict__ bq, const float* __restrict__ bk, const float* __restrict__ bv,
    u16* __restrict__ Wp, float* __restrict__ bp) {
  int i = blockIdx.x * 256 + threadIdx.x;
  if (i < 512 * 192) {
    int k = i / 192, r = i % 192, s = r >> 6, c = r & 63;
    const float* W = (s == 0) ? Wq : ((s == 1) ? Wk : Wv);
    Wp[i] = f2bf(W[k * 64 + c]);
  }
  if (i < 192) {
    int s = i >> 6, c = i & 63;
    bp[i] = ((s == 0) ? bq : ((s == 1) ? bk : bv))[c];
  }
}

// ---------------------------------------------------------------------------
// generic bf16 MFMA GEMM: C[M,N] = A[M,K] @ B[K,N] + bias.
// mode 0: plain (Cf fp32 and/or Cb bf16). mode 1: sigmoid -> Cf.
// mode 2: qkvT store -> Cf[sel][b][head][d][t] float4 along t (M=b*512+t, N=192).
__global__ __launch_bounds__(256) void gemm_bf16(
    const u16* __restrict__ A, const u16* __restrict__ B, const float* __restrict__ bias,
    float* __restrict__ Cf, u16* __restrict__ Cb, int M, int N, int K, int mode) {
  __shared__ u16 As[64][72];
  __shared__ u16 Bs[64][72];  // transposed: Bs[n][k]
  int tid = threadIdx.x;
  int tm = blockIdx.x * 64, tn = blockIdx.y * 64;
  int w = tid >> 6, L = tid & 63, m15 = L & 15, q = L >> 4;
  int lr = tid >> 3, lk = (tid & 7) * 8;

  f32x4 zero = {0.f, 0.f, 0.f, 0.f};
  f32x4 acc[4];
#pragma unroll
  for (int j = 0; j < 4; ++j) acc[j] = zero;

  for (int tk = 0; tk < K; tk += 64) {
#pragma unroll
    for (int rr = lr; rr < 64; rr += 32) {
      short8 v = *(const short8*)(A + (size_t)(tm + rr) * K + tk + lk);
      *(short8*)&As[rr][lk] = v;
    }
#pragma unroll
    for (int rr = lr; rr < 64; rr += 32) {
      short8 v = *(const short8*)(B + (size_t)(tk + rr) * N + tn + lk);
      const short* pv = (const short*)&v;
#pragma unroll
      for (int j = 0; j < 8; ++j) Bs[lk + j][rr] = (u16)pv[j];
    }
    __syncthreads();
#pragma unroll
    for (int ks = 0; ks < 2; ++ks) {
      int k0 = ks * 32 + q * 8;
      short8 a = *(const short8*)&As[w * 16 + m15][k0];
#pragma unroll
      for (int j = 0; j < 4; ++j) {
        short8 b = *(const short8*)&Bs[j * 16 + m15][k0];
        acc[j] = __builtin_amdgcn_mfma_f32_16x16x32_bf16(a, b, acc[j], 0, 0, 0);
      }
    }
    __syncthreads();
  }
  if (mode == 2) {
    int row0 = tm + w * 16 + q * 4;
    int bq_ = row0 >> 9, t0 = row0 & 511;
#pragma unroll
    for (int j = 0; j < 4; ++j) {
      int col = tn + j * 16 + m15;
      int sel = col >> 6, cc = col & 63, hd = cc >> 3, d = cc & 7;
      float bia = bias ? bias[col] : 0.f;
      f32x4 vv;
#pragma unroll
      for (int r = 0; r < 4; ++r) vv[r] = acc[j][r] + bia;
      *(f32x4*)(Cf + ((((size_t)sel * 16 + bq_) * 8 + hd) * 8 + d) * 512 + t0) = vv;
    }
    return;
  }
#pragma unroll
  for (int j = 0; j < 4; ++j) {
    int col = tn + j * 16 + m15;
    float bia = bias ? bias[col] : 0.f;
#pragma unroll
    for (int r = 0; r < 4; ++r) {
      int row = tm + w * 16 + q * 4 + r;
      float v = acc[j][r] + bia;
      if (mode == 1) v = sigmf(v);
      if (Cf) Cf[(size_t)row * N + col] = v;
      if (Cb) Cb[(size_t)row * N + col] = f2bf(v);
    }
  }
}

// ---------------------------------------------------------------------------
// Persistent LSTM scan + DVFS heaters. Grid 256 x 512:
//   wgs 0-7  : round-5 flag-protocol scan (unchanged — best measured).
//   wgs 8-255: heater loop — 4 independent VALU fma chains (no memory
//     traffic) to keep the clock governor at high frequency; poll
//     flags[64] (done) once per ~2k cycles; exit when scan finishes.
// Hypothesis under test: the ~4.4us/step scan cost is RTT inflated 3-4x by
// DVFS downclock at ~1% device utilization; heaters should cut it ~3x.
__global__ __launch_bounds__(512, 2) void lstm_kernel(
    const float* __restrict__ Wh,          // [512][2048] fp32
    const u16* __restrict__ xg,            // [8192][2048] bf16 (x@Wx + b)
    float* __restrict__ hs,                // [8192][512] fp32 out
    unsigned int* __restrict__ h_buf,      // [2][4096] u32 pairs
    int* __restrict__ flags)               // [65] zeroed before launch; [64]=done
{
  int tid = threadIdx.x;

  if (blockIdx.x >= 8) {
    // ---- heater ----
    float a0 = (float)tid + 1.f, a1 = a0 * 1.5f, a2 = a0 * 2.5f, a3 = a0 * 3.5f;
    const float b = 1.0001f, c = 0.9999f;
    const int* done = flags + 64;
    for (;;) {
#pragma unroll
      for (int i = 0; i < 128; ++i) {
        a0 = __builtin_fmaf(a0, b, c);
        a1 = __builtin_fmaf(a1, b, c);
        a2 = __builtin_fmaf(a2, b, c);
        a3 = __builtin_fmaf(a3, b, c);
      }
      if (__hip_atomic_load(done, __ATOMIC_RELAXED, __HIP_MEMORY_SCOPE_AGENT) != 0)
        break;
    }
    float s = a0 + a1 + a2 + a3;
    if (s == 123.456f) hs[0] = s;  // unreachable sink
    return;
  }

  // ---- scan (identical to round 5) ----
  __shared__ u16 hL[2][16][520];

  int wv = tid >> 6, L = tid & 63, m15 = L & 15, q = L >> 4;
  int u0w = blockIdx.x * 64 + wv * 8;  // first hidden unit of this wave

  // zero hL[0] (h_{-1} = 0)
  for (int i = tid; i < 16 * 520; i += 512) ((u16*)hL[0])[i] = 0;

  // preload Wh B-fragments into registers (step-invariant).
  short8 bfrag[16][2];
  float cst[4] = {0.f, 0.f, 0.f, 0.f};
#pragma unroll
  for (int kt = 0; kt < 16; ++kt) {
#pragma unroll
    for (int tl = 0; tl < 2; ++tl) {
      int n = tl * 16 + m15;
      int col = (n >> 3) * 512 + u0w + (n & 7);
      short8 tmp;
#pragma unroll
      for (int jj = 0; jj < 8; ++jj)
        tmp[jj] = (short)f2bf(Wh[(size_t)(kt * 32 + q * 8 + jj) * 2048 + col]);
      bfrag[kt][tl] = tmp;
    }
  }

  // xg prefetch for t=0
  float xv[4][4];
  if (m15 < 8) {
#pragma unroll
    for (int r = 0; r < 4; ++r) {
      size_t base = ((size_t)((q * 4 + r) * 512)) * 2048 + u0w + m15;
#pragma unroll
      for (int g = 0; g < 4; ++g) xv[g][r] = bf2f(xg[base + g * 512]);
    }
  }
  __syncthreads();

  int p = 0;
#pragma unroll 1
  for (int t = 0; t < 512; ++t) {
    unsigned int* hb32 = h_buf + (size_t)(t & 1) * 4096;

    // 4 independent MFMA chains of depth 8 (A rows = batch, from LDS)
    f32x4 z = {0.f, 0.f, 0.f, 0.f};
    f32x4 a0e = z, a0o = z, a1e = z, a1o = z;
#pragma unroll
    for (int kt = 0; kt < 8; ++kt) {
      short8 aE = *(const short8*)&hL[p][m15][(2 * kt) * 32 + q * 8];
      short8 aO = *(const short8*)&hL[p][m15][(2 * kt + 1) * 32 + q * 8];
      a0e = __builtin_amdgcn_mfma_f32_16x16x32_bf16(aE, bfrag[2 * kt][0], a0e, 0, 0, 0);
      a1e = __builtin_amdgcn_mfma_f32_16x16x32_bf16(aE, bfrag[2 * kt][1], a1e, 0, 0, 0);
      a0o = __builtin_amdgcn_mfma_f32_16x16x32_bf16(aO, bfrag[2 * kt + 1][0], a0o, 0, 0, 0);
      a1o = __builtin_amdgcn_mfma_f32_16x16x32_bf16(aO, bfrag[2 * kt + 1][1], a1o, 0, 0, 0);
    }
    f32x4 acc0, acc1;
#pragma unroll
    for (int r = 0; r < 4; ++r) { acc0[r] = a0e[r] + a0o[r]; acc1[r] = a1e[r] + a1o[r]; }
    // acc0 = i(m15<8)|f ; acc1 = g|o. Gather f,o into low lanes via lane^8.
    f32x4 accf, acco;
#pragma unroll
    for (int r = 0; r < 4; ++r) {
      accf[r] = __shfl_xor(acc0[r], 8);
      acco[r] = __shfl_xor(acc1[r], 8);
    }
    float hv[4] = {0.f, 0.f, 0.f, 0.f};
    unsigned int mybf[4] = {0, 0, 0, 0};
    if (m15 < 8) {
#pragma unroll
      for (int r = 0; r < 4; ++r) {
        float gi = acc0[r] + xv[0][r];
        float gf = accf[r] + xv[1][r];
        float gg = acc1[r] + xv[2][r];
        float go = acco[r] + xv[3][r];
        cst[r] = sigmf(gf) * cst[r] + sigmf(gi) * tanhfast(gg);
        hv[r] = sigmf(go) * tanhfast(cst[r]);
        mybf[r] = (unsigned int)f2bf(hv[r]);
      }
    }

    if (t == 511) {  // last step: no exchange needed
      if (m15 < 8) {
#pragma unroll
        for (int r = 0; r < 4; ++r)
          hs[((size_t)((q * 4 + r) * 512) + t) * 512 + u0w + m15] = hv[r];
      }
      break;
    }

    // h exchange stores (u32 pairs, agent relaxed)
#pragma unroll
    for (int r = 0; r < 4; ++r) {
      unsigned int ob = (unsigned int)__shfl_xor((int)mybf[r], 1);
      if (m15 < 8 && (m15 & 1) == 0) {
        unsigned int pv = mybf[r] | (ob << 16);
        __hip_atomic_store(&hb32[(q * 4 + r) * 256 + ((u0w + m15) >> 1)],
                           pv, __ATOMIC_RELAXED, __HIP_MEMORY_SCOPE_AGENT);
      }
    }
    // wave-local drain: our h stores acked at coherence point, then flag
    asm volatile("s_waitcnt vmcnt(0)" ::: "memory");
    if (L == 0)
      __hip_atomic_store(&flags[blockIdx.x * 8 + wv], t + 1,
                         __ATOMIC_RELAXED, __HIP_MEMORY_SCOPE_AGENT);

    // xg prefetch for t+1 (latency hidden under the exchange)
    if (m15 < 8) {
#pragma unroll
      for (int r = 0; r < 4; ++r) {
        size_t base = ((size_t)((q * 4 + r) * 512 + t + 1)) * 2048 + u0w + m15;
#pragma unroll
        for (int g = 0; g < 4; ++g) xv[g][r] = bf2f(xg[base + g * 512]);
      }
    }
    // hs output stores — deferred off the critical path
    if (m15 < 8) {
#pragma unroll
      for (int r = 0; r < 4; ++r)
        hs[((size_t)((q * 4 + r) * 512) + t) * 512 + u0w + m15] = hv[r];
    }

    // only wave 0 polls (other waves wait at the barrier — no vmem flood)
    if (wv == 0) {
      int target = t + 1;
      while (__hip_atomic_load(&flags[L], __ATOMIC_RELAXED,
                               __HIP_MEMORY_SCOPE_AGENT) < target) {
        __builtin_amdgcn_s_sleep(2);
      }
    }
    __syncthreads();

    // all-gather: 512 threads x 4 u64 = 16KB, coalesced
    const u64* hb64 = (const u64*)hb32;
    u64 v[4];
#pragma unroll
    for (int j = 0; j < 4; ++j)
      v[j] = __hip_atomic_load(&hb64[j * 512 + tid],
                               __ATOMIC_RELAXED, __HIP_MEMORY_SCOPE_AGENT);
#pragma unroll
    for (int j = 0; j < 4; ++j) {
      int e = j * 512 + tid;           // u64 index: b = e>>7, off = e&127
      *(u64*)&hL[p ^ 1][e >> 7][(e & 127) * 4] = v[j];
    }
    __syncthreads();
    p ^= 1;
  }

  // release heaters
  if (blockIdx.x == 0 && tid == 0)
    __hip_atomic_store(&flags[64], 1, __ATOMIC_RELAXED, __HIP_MEMORY_SCOPE_AGENT);
}

// ---------------------------------------------------------------------------
// LN1: y = LN(hs)*scale + bias + x ; writes fp32 + bf16. One wave per row.
__global__ __launch_bounds__(256) void ln1_kernel(
    const float* __restrict__ hsin, const float* __restrict__ x,
    const float* __restrict__ sc, const float* __restrict__ bi,
    float* __restrict__ hF, u16* __restrict__ hB) {
  int wv = threadIdx.x >> 6, ln = threadIdx.x & 63;
  size_t row = (size_t)blockIdx.x * 4 + wv;
  size_t rb = row * 512;
  float v[8];
  float s = 0.f;
#pragma unroll
  for (int j = 0; j < 8; ++j) { v[j] = hsin[rb + ln + j * 64]; s += v[j]; }
#pragma unroll
  for (int off = 32; off; off >>= 1) s += __shfl_xor(s, off);
  float mu = s * (1.f / 512.f);
  float vs = 0.f;
#pragma unroll
  for (int j = 0; j < 8; ++j) { float d = v[j] - mu; vs += d * d; }
#pragma unroll
  for (int off = 32; off; off >>= 1) vs += __shfl_xor(vs, off);
  float rs = rsqrtf(vs * (1.f / 512.f) + 1e-6f);
#pragma unroll
  for (int j = 0; j < 8; ++j) {
    int cc = ln + j * 64;
    float y = (v[j] - mu) * rs * sc[cc] + bi[cc] + x[rb + cc];
    hF[rb + cc] = y;
    hB[rb + cc] = f2bf(y);
  }
}

// LN2: out = LN(ao*gate + skip)*scale + bias
__global__ __launch_bounds__(256) void ln2_kernel(
    const float* __restrict__ ao, const float* __restrict__ gate,
    const float* __restrict__ skip, const float* __restrict__ sc,
    const float* __restrict__ bi, float* __restrict__ out) {
  int wv = threadIdx.x >> 6, ln = threadIdx.x & 63;
  size_t row = (size_t)blockIdx.x * 4 + wv;
  size_t rb = row * 512;
  float v[8];
  float s = 0.f;
#pragma unroll
  for (int j = 0; j < 8; ++j) {
    size_t ix = rb + ln + j * 64;
    v[j] = ao[ix] * gate[ix] + skip[ix];
    s += v[j];
  }
#pragma unroll
  for (int off = 32; off; off >>= 1) s += __shfl_xor(s, off);
  float mu = s * (1.f / 512.f);
  float vs = 0.f;
#pragma unroll
  for (int j = 0; j < 8; ++j) { float d = v[j] - mu; vs += d * d; }
#pragma unroll
  for (int off = 32; off; off >>= 1) vs += __shfl_xor(vs, off);
  float rs = rsqrtf(vs * (1.f / 512.f) + 1e-6f);
#pragma unroll
  for (int j = 0; j < 8; ++j) {
    int cc = ln + j * 64;
    out[rb + cc] = (v[j] - mu) * rs * sc[cc] + bi[cc];
  }
}

// ---------------------------------------------------------------------------
// attention on transposed qkvT[sel][b][head][d][t]: fully coalesced staging.
// one wg per (b, head); 512 threads = 1 query each; K/V in LDS [t][d] padded.
__global__ __launch_bounds__(512) void attn_kernel(const float* __restrict__ qkvT,
                                                   u16* __restrict__ ctx) {
  __shared__ float kL[512][9];
  __shared__ float vL[512][9];
  int tid = threadIdx.x;
  int b = blockIdx.x >> 3, hd = blockIdx.x & 7;
  const float* qb = qkvT + (((size_t)0 * 16 + b) * 8 + hd) * 8 * 512;
  const float* kb = qkvT + (((size_t)1 * 16 + b) * 8 + hd) * 8 * 512;
  const float* vb = qkvT + (((size_t)2 * 16 + b) * 8 + hd) * 8 * 512;
#pragma unroll
  for (int i = tid; i < 4096; i += 512) {
    int d = i >> 9, t = i & 511;
    kL[t][d] = kb[(size_t)d * 512 + t];
    vL[t][d] = vb[(size_t)d * 512 + t];
  }
  const float scl = 0.35355339059327373f;  // 1/sqrt(8)
  float qv[8];
#pragma unroll
  for (int d = 0; d < 8; ++d) qv[d] = qb[(size_t)d * 512 + tid] * scl;
  __syncthreads();
  float m = -1e30f, l = 0.f;
  float a[8] = {0, 0, 0, 0, 0, 0, 0, 0};
  for (int t2 = 0; t2 < 512; ++t2) {
    float s = 0.f;
#pragma unroll
    for (int d = 0; d < 8; ++d) s += qv[d] * kL[t2][d];
    float nm = fmaxf(m, s);
    float cor = __expf(m - nm);
    float e = __expf(s - nm);
    l = l * cor + e;
#pragma unroll
    for (int d = 0; d < 8; ++d) a[d] = a[d] * cor + e * vL[t2][d];
    m = nm;
  }
  float inv = 1.f / l;
  short8 o;
#pragma unroll
  for (int d = 0; d < 8; ++d) o[d] = (short)f2bf(a[d] * inv);
  *(short8*)(ctx + ((size_t)b * 512 + tid) * 64 + hd * 8) = o;
}

// ---------------------------------------------------------------------------
extern "C" void kernel_launch(void* const* d_in, const int* in_sizes, int n_in,
                              void* d_out, int out_size, void* d_ws, size_t ws_size,
                              hipStream_t stream) {
  (void)in_sizes; (void)n_in; (void)out_size; (void)ws_size;
  const float* x    = (const float*)d_in[0];
  const float* Wx   = (const float*)d_in[1];
  const float* Wh   = (const float*)d_in[2];
  const float* bls  = (const float*)d_in[3];
  const float* ln1s = (const float*)d_in[4];
  const float* ln1b = (const float*)d_in[5];
  const float* Wq   = (const float*)d_in[6];
  const float* bq   = (const float*)d_in[7];
  const float* Wk   = (const float*)d_in[8];
  const float* bk   = (const float*)d_in[9];
  const float* Wv   = (const float*)d_in[10];
  const float* bv   = (const float*)d_in[11];
  const float* Wo   = (const float*)d_in[12];
  const float* bo   = (const float*)d_in[13];
  const float* Wg   = (const float*)d_in[14];
  const float* bg   = (const float*)d_in[15];
  const float* ln2s = (const float*)d_in[16];
  const float* ln2b = (const float*)d_in[17];
  float* out = (float*)d_out;

  char* p = (char*)d_ws;
  auto alloc = [&](size_t bytes) -> char* {
    char* r = p;
    p += (bytes + 255) & ~(size_t)255;
    return r;
  };
  int* flags    = (int*)alloc(512);  // [0..63] step flags, [64] done
  unsigned int* h_buf = (unsigned int*)alloc((size_t)2 * 4096 * 4);
  u16* x_bf     = (u16*)alloc((size_t)8192 * 512 * 2);
  u16* Wx_bf    = (u16*)alloc((size_t)512 * 2048 * 2);
  u16* Wqkv_bf  = (u16*)alloc((size_t)512 * 192 * 2);
  float* bqkv   = (float*)alloc(192 * 4);
  u16* Wg_bf    = (u16*)alloc((size_t)512 * 512 * 2);
  u16* Wo_bf    = (u16*)alloc((size_t)64 * 512 * 2);
  u16* xg_bf    = (u16*)alloc((size_t)8192 * 2048 * 2);
  float* hs     = (float*)alloc((size_t)8192 * 512 * 4);
  float* hF     = (float*)alloc((size_t)8192 * 512 * 4);
  u16* hB       = (u16*)alloc((size_t)8192 * 512 * 2);
  float* qkvT   = (float*)alloc((size_t)3 * 16 * 8 * 8 * 512 * 4);
  float* gatep  = (float*)alloc((size_t)8192 * 512 * 4);
  u16* ctx      = (u16*)alloc((size_t)8192 * 64 * 2);
  float* ao     = (float*)alloc((size_t)8192 * 512 * 4);

  hipMemsetAsync(flags, 0, 512, stream);
  f2bf_kernel<<<16384, 256, 0, stream>>>(x, x_bf, 8192 * 512);
  f2bf_kernel<<<4096, 256, 0, stream>>>(Wx, Wx_bf, 512 * 2048);
  f2bf_kernel<<<1024, 256, 0, stream>>>(Wg, Wg_bf, 512 * 512);
  f2bf_kernel<<<128, 256, 0, stream>>>(Wo, Wo_bf, 64 * 512);
  pack_qkv_kernel<<<384, 256, 0, stream>>>(Wq, Wk, Wv, bq, bk, bv, Wqkv_bf, bqkv);

  // xg = x @ Wx + b  -> bf16 [8192,2048]
  gemm_bf16<<<dim3(128, 32), 256, 0, stream>>>(x_bf, Wx_bf, bls, nullptr, xg_bf,
                                               8192, 2048, 512, 0);
  // LSTM scan (wgs 0-7) + DVFS heaters (wgs 8-255) -> hs fp32 [8192,512]
  lstm_kernel<<<256, 512, 0, stream>>>(Wh, xg_bf, hs, h_buf, flags);
  // h = LN(hs)+x  -> hF fp32, hB bf16
  ln1_kernel<<<2048, 256, 0, stream>>>(hs, x, ln1s, ln1b, hF, hB);
  // qkv = h @ [Wq|Wk|Wv] + b  -> qkvT[sel][b][head][d][t] fp32
  gemm_bf16<<<dim3(128, 3), 256, 0, stream>>>(hB, Wqkv_bf, bqkv, qkvT, nullptr,
                                              8192, 192, 512, 2);
  // gate = sigmoid(h @ Wg + bg)  -> fp32 [8192,512]
  gemm_bf16<<<dim3(128, 8), 256, 0, stream>>>(hB, Wg_bf, bg, gatep, nullptr,
                                              8192, 512, 512, 1);
  // attention -> ctx bf16 [8192,64]
  attn_kernel<<<128, 512, 0, stream>>>(qkvT, ctx);
  // attn_out = ctx @ Wo + bo -> fp32 [8192,512]
  gemm_bf16<<<dim3(128, 8), 256, 0, stream>>>(ctx, Wo_bf, bo, ao, nullptr,
                                              8192, 512, 64, 0);
  // out = LN(ao*gate + h)
  ln2_kernel<<<2048, 256, 0, stream>>>(ao, gatep, hF, ln2s, ln2b, out);
}

// Round 8
// 2375.559 us; speedup vs baseline: 1.1924x; 1.1204x over previous
//
#include <hip/hip_runtime.h>

typedef unsigned short u16;
typedef unsigned int u32;
typedef unsigned long long u64;
typedef __attribute__((ext_vector_type(8))) short short8;
typedef __attribute__((ext_vector_type(4))) float f32x4;

__device__ __forceinline__ float bf2f(u16 u) {
  union { float f; unsigned int i; } x; x.i = ((unsigned int)u) << 16; return x.f;
}
__device__ __forceinline__ u16 f2bf(float f) {
  union { float f; unsigned int i; } x; x.f = f;
  unsigned int r = x.i + 0x7FFFu + ((x.i >> 16) & 1u);
  return (u16)(r >> 16);
}
__device__ __forceinline__ float sigmf(float x) { return 1.f / (1.f + __expf(-x)); }
__device__ __forceinline__ float tanhfast(float x) { return 1.f - 2.f / (__expf(2.f * x) + 1.f); }

// ---------------------------------------------------------------------------
// elementwise fp32 -> bf16 convert
__global__ __launch_bounds__(256) void f2bf_kernel(const float* __restrict__ src,
                                                   u16* __restrict__ dst, int n) {
  int i = blockIdx.x * 256 + threadIdx.x;
  if (i < n) dst[i] = f2bf(src[i]);
}

// pack Wq|Wk|Wv -> [512][192] bf16, bq|bk|bv -> [192] fp32
__global__ __launch_bounds__(256) void pack_qkv_kernel(
    const float* __restrict__ Wq, const float* __restrict__ Wk, const float* __restrict__ Wv,
    const float* __restrict__ bq, const float* __restrict__ bk, const float* __restrict__ bv,
    u16* __restrict__ Wp, float* __restrict__ bp) {
  int i = blockIdx.x * 256 + threadIdx.x;
  if (i < 512 * 192) {
    int k = i / 192, r = i % 192, s = r >> 6, c = r & 63;
    const float* W = (s == 0) ? Wq : ((s == 1) ? Wk : Wv);
    Wp[i] = f2bf(W[k * 64 + c]);
  }
  if (i < 192) {
    int s = i >> 6, c = i & 63;
    bp[i] = ((s == 0) ? bq : ((s == 1) ? bk : bv))[c];
  }
}

// ---------------------------------------------------------------------------
// generic bf16 MFMA GEMM: C[M,N] = A[M,K] @ B[K,N] + bias.
// mode 0: plain (Cf fp32 and/or Cb bf16). mode 1: sigmoid -> Cf.
// mode 2: qkvT store -> Cf[sel][b][head][d][t] float4 along t (M=b*512+t, N=192).
__global__ __launch_bounds__(256) void gemm_bf16(
    const u16* __restrict__ A, const u16* __restrict__ B, const float* __restrict__ bias,
    float* __restrict__ Cf, u16* __restrict__ Cb, int M, int N, int K, int mode) {
  __shared__ u16 As[64][72];
  __shared__ u16 Bs[64][72];  // transposed: Bs[n][k]
  int tid = threadIdx.x;
  int tm = blockIdx.x * 64, tn = blockIdx.y * 64;
  int w = tid >> 6, L = tid & 63, m15 = L & 15, q = L >> 4;
  int lr = tid >> 3, lk = (tid & 7) * 8;

  f32x4 zero = {0.f, 0.f, 0.f, 0.f};
  f32x4 acc[4];
#pragma unroll
  for (int j = 0; j < 4; ++j) acc[j] = zero;

  for (int tk = 0; tk < K; tk += 64) {
#pragma unroll
    for (int rr = lr; rr < 64; rr += 32) {
      short8 v = *(const short8*)(A + (size_t)(tm + rr) * K + tk + lk);
      *(short8*)&As[rr][lk] = v;
    }
#pragma unroll
    for (int rr = lr; rr < 64; rr += 32) {
      short8 v = *(const short8*)(B + (size_t)(tk + rr) * N + tn + lk);
      const short* pv = (const short*)&v;
#pragma unroll
      for (int j = 0; j < 8; ++j) Bs[lk + j][rr] = (u16)pv[j];
    }
    __syncthreads();
#pragma unroll
    for (int ks = 0; ks < 2; ++ks) {
      int k0 = ks * 32 + q * 8;
      short8 a = *(const short8*)&As[w * 16 + m15][k0];
#pragma unroll
      for (int j = 0; j < 4; ++j) {
        short8 b = *(const short8*)&Bs[j * 16 + m15][k0];
        acc[j] = __builtin_amdgcn_mfma_f32_16x16x32_bf16(a, b, acc[j], 0, 0, 0);
      }
    }
    __syncthreads();
  }
  if (mode == 2) {
    int row0 = tm + w * 16 + q * 4;
    int bq_ = row0 >> 9, t0 = row0 & 511;
#pragma unroll
    for (int j = 0; j < 4; ++j) {
      int col = tn + j * 16 + m15;
      int sel = col >> 6, cc = col & 63, hd = cc >> 3, d = cc & 7;
      float bia = bias ? bias[col] : 0.f;
      f32x4 vv;
#pragma unroll
      for (int r = 0; r < 4; ++r) vv[r] = acc[j][r] + bia;
      *(f32x4*)(Cf + ((((size_t)sel * 16 + bq_) * 8 + hd) * 8 + d) * 512 + t0) = vv;
    }
    return;
  }
#pragma unroll
  for (int j = 0; j < 4; ++j) {
    int col = tn + j * 16 + m15;
    float bia = bias ? bias[col] : 0.f;
#pragma unroll
    for (int r = 0; r < 4; ++r) {
      int row = tm + w * 16 + q * 4 + r;
      float v = acc[j][r] + bia;
      if (mode == 1) v = sigmf(v);
      if (Cf) Cf[(size_t)row * N + col] = v;
      if (Cb) Cb[(size_t)row * N + col] = f2bf(v);
    }
  }
}

// ---------------------------------------------------------------------------
// Persistent LSTM scan: 8 wgs x 512 threads; wave w of wg g owns hidden
// units 64g+8w..+7 (32 Wh gate-columns in VGPRs).
// Tagged slack protocol (flag-free, drain-free, ~1 RTT/step):
//   1. tagged u64 {t+1, 2xbf16} h stores (relaxed agent, fire-and-forget)
//   2. hs stores + xg(t+1) prefetch issued NOW — acked during the slack,
//      so the gather check never waits on them
//   3. ~1000-cycle s_sleep slack: all wgs' data reaches the coherence point
//      BEFORE our gather loads arrive there (check is a snapshot of load
//      arrival time, so slack must precede ISSUE, not the check)
//   4. gather issue -> tag check (expected first-try pass; selective-retry
//      loop kept purely as a correctness net)
//   5. LDS fill, ONE __syncthreads.
// h_buf parity-double-buffered; tag==t+1 exact (stale parity = t-1, 0xAA
// poison never matches).
__global__ __launch_bounds__(512, 2) void lstm_kernel(
    const float* __restrict__ Wh,   // [512][2048] fp32
    const u16* __restrict__ xg,     // [8192][2048] bf16 (x@Wx + b)
    float* __restrict__ hs,         // [8192][512] fp32 out
    u64* __restrict__ h_buf)        // [2][4096] {tag, 2xbf16}
{
  __shared__ u16 hL[2][16][520];

  int tid = threadIdx.x;
  int wv = tid >> 6, L = tid & 63, m15 = L & 15, q = L >> 4;
  int u0w = blockIdx.x * 64 + wv * 8;  // first hidden unit of this wave

  // zero hL[0] (h_{-1} = 0)
  for (int i = tid; i < 16 * 520; i += 512) ((u16*)hL[0])[i] = 0;

  // preload Wh B-fragments into registers (step-invariant).
  // bfrag[kt][tl]: B[k=kt*32+q*8+jj][n=tl*16+m15], col=(n>>3)*512+u0w+(n&7)
  short8 bfrag[16][2];
  float cst[4] = {0.f, 0.f, 0.f, 0.f};
#pragma unroll
  for (int kt = 0; kt < 16; ++kt) {
#pragma unroll
    for (int tl = 0; tl < 2; ++tl) {
      int n = tl * 16 + m15;
      int col = (n >> 3) * 512 + u0w + (n & 7);
      short8 tmp;
#pragma unroll
      for (int jj = 0; jj < 8; ++jj)
        tmp[jj] = (short)f2bf(Wh[(size_t)(kt * 32 + q * 8 + jj) * 2048 + col]);
      bfrag[kt][tl] = tmp;
    }
  }

  // xg prefetch for t=0
  float xv[4][4];
  if (m15 < 8) {
#pragma unroll
    for (int r = 0; r < 4; ++r) {
      size_t base = ((size_t)((q * 4 + r) * 512)) * 2048 + u0w + m15;
#pragma unroll
      for (int g = 0; g < 4; ++g) xv[g][r] = bf2f(xg[base + g * 512]);
    }
  }
  __syncthreads();

  int p = 0;
#pragma unroll 1
  for (int t = 0; t < 512; ++t) {
    u64* hb = h_buf + (size_t)(t & 1) * 4096;

    // 4 independent MFMA chains of depth 8 (A rows = batch, from LDS)
    f32x4 z = {0.f, 0.f, 0.f, 0.f};
    f32x4 a0e = z, a0o = z, a1e = z, a1o = z;
#pragma unroll
    for (int kt = 0; kt < 8; ++kt) {
      short8 aE = *(const short8*)&hL[p][m15][(2 * kt) * 32 + q * 8];
      short8 aO = *(const short8*)&hL[p][m15][(2 * kt + 1) * 32 + q * 8];
      a0e = __builtin_amdgcn_mfma_f32_16x16x32_bf16(aE, bfrag[2 * kt][0], a0e, 0, 0, 0);
      a1e = __builtin_amdgcn_mfma_f32_16x16x32_bf16(aE, bfrag[2 * kt][1], a1e, 0, 0, 0);
      a0o = __builtin_amdgcn_mfma_f32_16x16x32_bf16(aO, bfrag[2 * kt + 1][0], a0o, 0, 0, 0);
      a1o = __builtin_amdgcn_mfma_f32_16x16x32_bf16(aO, bfrag[2 * kt + 1][1], a1o, 0, 0, 0);
    }
    f32x4 acc0, acc1;
#pragma unroll
    for (int r = 0; r < 4; ++r) { acc0[r] = a0e[r] + a0o[r]; acc1[r] = a1e[r] + a1o[r]; }
    // acc0 = i(m15<8)|f ; acc1 = g|o. Gather f,o into low lanes via lane^8.
    f32x4 accf, acco;
#pragma unroll
    for (int r = 0; r < 4; ++r) {
      accf[r] = __shfl_xor(acc0[r], 8);
      acco[r] = __shfl_xor(acc1[r], 8);
    }
    float hv[4] = {0.f, 0.f, 0.f, 0.f};
    unsigned int mybf[4] = {0, 0, 0, 0};
    if (m15 < 8) {
#pragma unroll
      for (int r = 0; r < 4; ++r) {
        float gi = acc0[r] + xv[0][r];
        float gf = accf[r] + xv[1][r];
        float gg = acc1[r] + xv[2][r];
        float go = acco[r] + xv[3][r];
        cst[r] = sigmf(gf) * cst[r] + sigmf(gi) * tanhfast(gg);
        hv[r] = sigmf(go) * tanhfast(cst[r]);
        mybf[r] = (unsigned int)f2bf(hv[r]);
      }
    }

    if (t == 511) {  // last step: no exchange needed
      if (m15 < 8) {
#pragma unroll
        for (int r = 0; r < 4; ++r)
          hs[((size_t)((q * 4 + r) * 512) + t) * 512 + u0w + m15] = hv[r];
      }
      break;
    }

    // (1) tagged h stores: ONE relaxed agent u64 per pair — fire and forget
    unsigned int target = (unsigned int)(t + 1);
#pragma unroll
    for (int r = 0; r < 4; ++r) {
      unsigned int ob = (unsigned int)__shfl_xor((int)mybf[r], 1);
      if (m15 < 8 && (m15 & 1) == 0) {
        u64 val = ((u64)target << 32) | (u64)(mybf[r] | (ob << 16));
        __hip_atomic_store(&hb[(q * 4 + r) * 256 + ((u0w + m15) >> 1)], val,
                           __ATOMIC_RELAXED, __HIP_MEMORY_SCOPE_AGENT);
      }
    }

    // (2) off-path vmem NOW: acks/latency covered by the slack below
    if (m15 < 8) {
#pragma unroll
      for (int r = 0; r < 4; ++r)
        hs[((size_t)((q * 4 + r) * 512) + t) * 512 + u0w + m15] = hv[r];
#pragma unroll
      for (int r = 0; r < 4; ++r) {
        size_t base = ((size_t)((q * 4 + r) * 512 + t + 1)) * 2048 + u0w + m15;
#pragma unroll
        for (int g = 0; g < 4; ++g) xv[g][r] = bf2f(xg[base + g * 512]);
      }
    }

    // (3) slack: let every wg's tagged data land at the coherence point
    __builtin_amdgcn_s_sleep(8);
    __builtin_amdgcn_s_sleep(8);

    // (4) gather issue: 8 u64 per thread (32KB total), coalesced
    u64 v[8];
#pragma unroll
    for (int j = 0; j < 8; ++j)
      v[j] = __hip_atomic_load(&hb[j * 512 + tid],
                               __ATOMIC_RELAXED, __HIP_MEMORY_SCOPE_AGENT);

    // tag-check + selective retry (expected: zero rounds)
    for (;;) {
      unsigned int need = 0;
#pragma unroll
      for (int j = 0; j < 8; ++j)
        need |= ((unsigned int)((unsigned int)(v[j] >> 32) != target)) << j;
      if (need == 0) break;
#pragma unroll
      for (int j = 0; j < 8; ++j)
        if (need & (1u << j))
          v[j] = __hip_atomic_load(&hb[j * 512 + tid],
                                   __ATOMIC_RELAXED, __HIP_MEMORY_SCOPE_AGENT);
    }

    // (5) LDS fill: e = j*512+tid -> row e>>8, pair e&255 (u32 = 2 bf16)
#pragma unroll
    for (int j = 0; j < 8; ++j) {
      int e = j * 512 + tid;
      *(u32*)&hL[p ^ 1][e >> 8][(e & 255) * 2] = (u32)v[j];
    }
    __syncthreads();
    p ^= 1;
  }
}

// ---------------------------------------------------------------------------
// LN1: y = LN(hs)*scale + bias + x ; writes fp32 + bf16. One wave per row.
__global__ __launch_bounds__(256) void ln1_kernel(
    const float* __restrict__ hsin, const float* __restrict__ x,
    const float* __restrict__ sc, const float* __restrict__ bi,
    float* __restrict__ hF, u16* __restrict__ hB) {
  int wv = threadIdx.x >> 6, ln = threadIdx.x & 63;
  size_t row = (size_t)blockIdx.x * 4 + wv;
  size_t rb = row * 512;
  float v[8];
  float s = 0.f;
#pragma unroll
  for (int j = 0; j < 8; ++j) { v[j] = hsin[rb + ln + j * 64]; s += v[j]; }
#pragma unroll
  for (int off = 32; off; off >>= 1) s += __shfl_xor(s, off);
  float mu = s * (1.f / 512.f);
  float vs = 0.f;
#pragma unroll
  for (int j = 0; j < 8; ++j) { float d = v[j] - mu; vs += d * d; }
#pragma unroll
  for (int off = 32; off; off >>= 1) vs += __shfl_xor(vs, off);
  float rs = rsqrtf(vs * (1.f / 512.f) + 1e-6f);
#pragma unroll
  for (int j = 0; j < 8; ++j) {
    int cc = ln + j * 64;
    float y = (v[j] - mu) * rs * sc[cc] + bi[cc] + x[rb + cc];
    hF[rb + cc] = y;
    hB[rb + cc] = f2bf(y);
  }
}

// LN2: out = LN(ao*gate + skip)*scale + bias
__global__ __launch_bounds__(256) void ln2_kernel(
    const float* __restrict__ ao, const float* __restrict__ gate,
    const float* __restrict__ skip, const float* __restrict__ sc,
    const float* __restrict__ bi, float* __restrict__ out) {
  int wv = threadIdx.x >> 6, ln = threadIdx.x & 63;
  size_t row = (size_t)blockIdx.x * 4 + wv;
  size_t rb = row * 512;
  float v[8];
  float s = 0.f;
#pragma unroll
  for (int j = 0; j < 8; ++j) {
    size_t ix = rb + ln + j * 64;
    v[j] = ao[ix] * gate[ix] + skip[ix];
    s += v[j];
  }
#pragma unroll
  for (int off = 32; off; off >>= 1) s += __shfl_xor(s, off);
  float mu = s * (1.f / 512.f);
  float vs = 0.f;
#pragma unroll
  for (int j = 0; j < 8; ++j) { float d = v[j] - mu; vs += d * d; }
#pragma unroll
  for (int off = 32; off; off >>= 1) vs += __shfl_xor(vs, off);
  float rs = rsqrtf(vs * (1.f / 512.f) + 1e-6f);
#pragma unroll
  for (int j = 0; j < 8; ++j) {
    int cc = ln + j * 64;
    out[rb + cc] = (v[j] - mu) * rs * sc[cc] + bi[cc];
  }
}

// ---------------------------------------------------------------------------
// attention on transposed qkvT[sel][b][head][d][t]: fully coalesced staging.
// one wg per (b, head); 512 threads = 1 query each; K/V in LDS [t][d] padded.
__global__ __launch_bounds__(512) void attn_kernel(const float* __restrict__ qkvT,
                                                   u16* __restrict__ ctx) {
  __shared__ float kL[512][9];
  __shared__ float vL[512][9];
  int tid = threadIdx.x;
  int b = blockIdx.x >> 3, hd = blockIdx.x & 7;
  const float* qb = qkvT + (((size_t)0 * 16 + b) * 8 + hd) * 8 * 512;
  const float* kb = qkvT + (((size_t)1 * 16 + b) * 8 + hd) * 8 * 512;
  const float* vb = qkvT + (((size_t)2 * 16 + b) * 8 + hd) * 8 * 512;
#pragma unroll
  for (int i = tid; i < 4096; i += 512) {
    int d = i >> 9, t = i & 511;
    kL[t][d] = kb[(size_t)d * 512 + t];
    vL[t][d] = vb[(size_t)d * 512 + t];
  }
  const float scl = 0.35355339059327373f;  // 1/sqrt(8)
  float qv[8];
#pragma unroll
  for (int d = 0; d < 8; ++d) qv[d] = qb[(size_t)d * 512 + tid] * scl;
  __syncthreads();
  float m = -1e30f, l = 0.f;
  float a[8] = {0, 0, 0, 0, 0, 0, 0, 0};
  for (int t2 = 0; t2 < 512; ++t2) {
    float s = 0.f;
#pragma unroll
    for (int d = 0; d < 8; ++d) s += qv[d] * kL[t2][d];
    float nm = fmaxf(m, s);
    float cor = __expf(m - nm);
    float e = __expf(s - nm);
    l = l * cor + e;
#pragma unroll
    for (int d = 0; d < 8; ++d) a[d] = a[d] * cor + e * vL[t2][d];
    m = nm;
  }
  float inv = 1.f / l;
  short8 o;
#pragma unroll
  for (int d = 0; d < 8; ++d) o[d] = (short)f2bf(a[d] * inv);
  *(short8*)(ctx + ((size_t)b * 512 + tid) * 64 + hd * 8) = o;
}

// ---------------------------------------------------------------------------
extern "C" void kernel_launch(void* const* d_in, const int* in_sizes, int n_in,
                              void* d_out, int out_size, void* d_ws, size_t ws_size,
                              hipStream_t stream) {
  (void)in_sizes; (void)n_in; (void)out_size; (void)ws_size;
  const float* x    = (const float*)d_in[0];
  const float* Wx   = (const float*)d_in[1];
  const float* Wh   = (const float*)d_in[2];
  const float* bls  = (const float*)d_in[3];
  const float* ln1s = (const float*)d_in[4];
  const float* ln1b = (const float*)d_in[5];
  const float* Wq   = (const float*)d_in[6];
  const float* bq   = (const float*)d_in[7];
  const float* Wk   = (const float*)d_in[8];
  const float* bk   = (const float*)d_in[9];
  const float* Wv   = (const float*)d_in[10];
  const float* bv   = (const float*)d_in[11];
  const float* Wo   = (const float*)d_in[12];
  const float* bo   = (const float*)d_in[13];
  const float* Wg   = (const float*)d_in[14];
  const float* bg   = (const float*)d_in[15];
  const float* ln2s = (const float*)d_in[16];
  const float* ln2b = (const float*)d_in[17];
  float* out = (float*)d_out;

  char* p = (char*)d_ws;
  auto alloc = [&](size_t bytes) -> char* {
    char* r = p;
    p += (bytes + 255) & ~(size_t)255;
    return r;
  };
  u64* h_buf    = (u64*)alloc((size_t)2 * 4096 * 8);
  u16* x_bf     = (u16*)alloc((size_t)8192 * 512 * 2);
  u16* Wx_bf    = (u16*)alloc((size_t)512 * 2048 * 2);
  u16* Wqkv_bf  = (u16*)alloc((size_t)512 * 192 * 2);
  float* bqkv   = (float*)alloc(192 * 4);
  u16* Wg_bf    = (u16*)alloc((size_t)512 * 512 * 2);
  u16* Wo_bf    = (u16*)alloc((size_t)64 * 512 * 2);
  u16* xg_bf    = (u16*)alloc((size_t)8192 * 2048 * 2);
  float* hs     = (float*)alloc((size_t)8192 * 512 * 4);
  float* hF     = (float*)alloc((size_t)8192 * 512 * 4);
  u16* hB       = (u16*)alloc((size_t)8192 * 512 * 2);
  float* qkvT   = (float*)alloc((size_t)3 * 16 * 8 * 8 * 512 * 4);
  float* gatep  = (float*)alloc((size_t)8192 * 512 * 4);
  u16* ctx      = (u16*)alloc((size_t)8192 * 64 * 2);
  float* ao     = (float*)alloc((size_t)8192 * 512 * 4);

  f2bf_kernel<<<16384, 256, 0, stream>>>(x, x_bf, 8192 * 512);
  f2bf_kernel<<<4096, 256, 0, stream>>>(Wx, Wx_bf, 512 * 2048);
  f2bf_kernel<<<1024, 256, 0, stream>>>(Wg, Wg_bf, 512 * 512);
  f2bf_kernel<<<128, 256, 0, stream>>>(Wo, Wo_bf, 64 * 512);
  pack_qkv_kernel<<<384, 256, 0, stream>>>(Wq, Wk, Wv, bq, bk, bv, Wqkv_bf, bqkv);

  // xg = x @ Wx + b  -> bf16 [8192,2048]
  gemm_bf16<<<dim3(128, 32), 256, 0, stream>>>(x_bf, Wx_bf, bls, nullptr, xg_bf,
                                               8192, 2048, 512, 0);
  // LSTM scan -> hs fp32 [8192,512]
  lstm_kernel<<<8, 512, 0, stream>>>(Wh, xg_bf, hs, h_buf);
  // h = LN(hs)+x  -> hF fp32, hB bf16
  ln1_kernel<<<2048, 256, 0, stream>>>(hs, x, ln1s, ln1b, hF, hB);
  // qkv = h @ [Wq|Wk|Wv] + b  -> qkvT[sel][b][head][d][t] fp32
  gemm_bf16<<<dim3(128, 3), 256, 0, stream>>>(hB, Wqkv_bf, bqkv, qkvT, nullptr,
                                              8192, 192, 512, 2);
  // gate = sigmoid(h @ Wg + bg)  -> fp32 [8192,512]
  gemm_bf16<<<dim3(128, 8), 256, 0, stream>>>(hB, Wg_bf, bg, gatep, nullptr,
                                              8192, 512, 512, 1);
  // attention -> ctx bf16 [8192,64]
  attn_kernel<<<128, 512, 0, stream>>>(qkvT, ctx);
  // attn_out = ctx @ Wo + bo -> fp32 [8192,512]
  gemm_bf16<<<dim3(128, 8), 256, 0, stream>>>(ctx, Wo_bf, bo, ao, nullptr,
                                              8192, 512, 64, 0);
  // out = LN(ao*gate + h)
  ln2_kernel<<<2048, 256, 0, stream>>>(ao, gatep, hF, ln2s, ln2b, out);
}